// Round 2
// baseline (255.786 us; speedup 1.0000x reference)
//
#include <hip/hip_runtime.h>
#include <math.h>

// NetVLAD: N=32, C=512, P=1024, K=64, ALPHA=100
#define ALPHA 100.0f
#define EPSN 1e-12f

// ---------------- prep: vt[c][k] = v[k][c]; bias[k] = -alpha*||v_k|| --------
__global__ __launch_bounds__(64) void prep_kernel(const float* __restrict__ v,
                                                  float* __restrict__ vt,
                                                  float* __restrict__ bias) {
    int k = blockIdx.x;      // 0..63
    int lane = threadIdx.x;  // 0..63
    const float* row = v + k * 512;
    float ssq = 0.f;
#pragma unroll
    for (int i = 0; i < 8; ++i) {
        float xv = row[lane + 64 * i];
        ssq = fmaf(xv, xv, ssq);
    }
#pragma unroll
    for (int off = 32; off > 0; off >>= 1) ssq += __shfl_xor(ssq, off, 64);
    if (lane == 0) bias[k] = -ALPHA * sqrtf(ssq);
#pragma unroll
    for (int i = 0; i < 8; ++i) {
        int c = lane + 64 * i;
        vt[c * 64 + k] = row[c];
    }
}

// ---------------- assign: lane=p, 64 k per thread, c-split 8 waves ----------
// grid 512 blocks x 512 threads. Each block: 64 p's, waves cover c-octants.
__global__ __launch_bounds__(512, 4) void assign_kernel(
    const float* __restrict__ x, const float* __restrict__ vt,
    const float* __restrict__ bias, float* __restrict__ aT,
    float* __restrict__ asum, float* __restrict__ s_inv) {
    int tid = threadIdx.x;
    int l = tid & 63;
    int w = tid >> 6;  // 0..7
    int wu = __builtin_amdgcn_readfirstlane(w);
    int c0 = wu << 6;               // wave's c-range base (uniform)
    int g = blockIdx.x * 64 + l;    // global p id 0..32767
    int n = g >> 10;
    const float* xp = x + (size_t)n * 524288 + (g & 1023);

    float dot[64];
#pragma unroll
    for (int k = 0; k < 64; ++k) dot[k] = 0.f;
    float ssq = 0.f;
#pragma unroll 2
    for (int i = 0; i < 64; ++i) {
        int c = c0 + i;
        float xv = xp[(size_t)c << 10];  // coalesced 256B per wave
        ssq = fmaf(xv, xv, ssq);
        const float* vr = vt + (c << 6);  // wave-uniform -> s_load x4 dwordx16
#pragma unroll
        for (int k = 0; k < 64; ++k) dot[k] = fmaf(xv, vr[k], dot[k]);
    }

    // two-round cross-wave combine: 65 floats/thread (64 dot + ssq)
    __shared__ float red[4][64][66];
    if (w >= 4) {
#pragma unroll
        for (int k = 0; k < 64; ++k) red[w - 4][l][k] = dot[k];
        red[w - 4][l][64] = ssq;
    }
    __syncthreads();
    if (w < 4) {
#pragma unroll
        for (int k = 0; k < 64; ++k) dot[k] += red[w][l][k];
        ssq += red[w][l][64];
    }
    __syncthreads();
    if (w >= 1 && w < 4) {
#pragma unroll
        for (int k = 0; k < 64; ++k) red[w][l][k] = dot[k];
        red[w][l][64] = ssq;
    }
    __syncthreads();
    if (w == 0) {
        // wave 0: full logits in registers -> softmax, no cross-lane reduce
#pragma unroll
        for (int k = 0; k < 64; ++k)
            dot[k] += red[1][l][k] + red[2][l][k] + red[3][l][k];
        ssq += red[1][l][64] + red[2][l][64] + red[3][l][64];
        float sinv = 1.0f / fmaxf(sqrtf(ssq), EPSN);
        s_inv[g] = sinv;
        float twoAs = 2.0f * ALPHA * sinv;
        float m = -INFINITY;
#pragma unroll
        for (int k = 0; k < 64; ++k) {
            dot[k] = fmaf(twoAs, dot[k], bias[k]);
            m = fmaxf(m, dot[k]);
        }
        float s = 0.f;
#pragma unroll
        for (int k = 0; k < 64; ++k) {
            dot[k] = expf(dot[k] - m);
            s += dot[k];
        }
        float rs = 1.0f / s;
#pragma unroll
        for (int k = 0; k < 64; ++k) red[0][l][k] = dot[k] * rs;
    }
    __syncthreads();
    // all 8 waves: store one k-octant of aT + asum atomics (dynamic LDS idx)
    float* ap = aT + (size_t)n * 65536 + (g & 1023);
#pragma unroll
    for (int j = 0; j < 8; ++j) {
        int kk = wu * 8 + j;
        float av = red[0][l][kk];
        ap[(size_t)kk << 10] = av;
        float vs = av;
#pragma unroll
        for (int off = 32; off > 0; off >>= 1) vs += __shfl_xor(vs, off, 64);
        if (l == 0) atomicAdd(&asum[n * 64 + kk], vs);
    }
}

// ---------------- vlad: block (n, 64-c chunk); lane=c; 8 waves = p-slabs ----
// acc[64 k] per thread; a[k][p] streamed via s_loads; x via LDS transpose.
// Fuses -asum*v correction, writes raw-corrected out + knorm (ssq) atomics.
__global__ __launch_bounds__(512, 2) void vlad_kernel(
    const float* __restrict__ x, const float* __restrict__ aT,
    const float* __restrict__ s_inv, const float* __restrict__ asum,
    const float* __restrict__ vocabs, float* __restrict__ out,
    float* __restrict__ knorm) {
    int n = blockIdx.y;
    int cb = blockIdx.x << 6;
    int tid = threadIdx.x;
    int l = tid & 63;  // c offset within chunk
    int wu = __builtin_amdgcn_readfirstlane(tid >> 6);  // 0..7 p-slab
    int c = cb + l;

    __shared__ float smem[16640];  // 66560B: xt[256][65]  union  red2[4][64][65]

    float acc[64];
#pragma unroll
    for (int k = 0; k < 64; ++k) acc[k] = 0.f;

    int pl = tid & 255;      // staging p (invariant per thread)
    int ch = tid >> 8;       // 0/1
    const float* xb = x + (size_t)n * 524288;
    const float* sb = s_inv + n * 1024;
    const float* ab0 = aT + (size_t)n * 65536;

    for (int sc = 0; sc < 4; ++sc) {
        int p_base = sc << 8;
        __syncthreads();  // protect xt from previous iteration's readers
        float sv = sb[p_base + pl];
#pragma unroll
        for (int i = 0; i < 32; ++i) {
            int c_l = 2 * i + ch;
            float val = xb[(size_t)(cb + c_l) * 1024 + p_base + pl];
            smem[pl * 65 + c_l] = val * sv;  // bank (pl+c_l)%32: conflict-free
        }
        __syncthreads();
        // cache this slab's 32 x-values in regs
        float xv[32];
#pragma unroll
        for (int j = 0; j < 32; ++j) xv[j] = smem[(wu * 32 + j) * 65 + l];
        const float* ab = ab0 + p_base + wu * 32;  // uniform base
#pragma unroll
        for (int k = 0; k < 64; ++k) {
            const float* ar = ab + (k << 10);  // wave-uniform -> s_loads
#pragma unroll
            for (int j = 0; j < 32; ++j) acc[k] = fmaf(ar[j], xv[j], acc[k]);
        }
    }

    // cross-wave (p-slab) combine, two rounds, reusing smem
    __syncthreads();
    if (wu >= 4) {
#pragma unroll
        for (int k = 0; k < 64; ++k) smem[((wu - 4) * 64 + l) * 65 + k] = acc[k];
    }
    __syncthreads();
    if (wu < 4) {
#pragma unroll
        for (int k = 0; k < 64; ++k) acc[k] += smem[(wu * 64 + l) * 65 + k];
    }
    __syncthreads();
    if (wu < 4) {
#pragma unroll
        for (int k = 0; k < 64; ++k) smem[(wu * 64 + l) * 65 + k] = acc[k];
    }
    __syncthreads();
    // each wave finalizes one k-octant: combine 4 bufs, -asum*v, store, knorm
#pragma unroll
    for (int j = 0; j < 8; ++j) {
        int kk = wu * 8 + j;
        float val = smem[(0 * 64 + l) * 65 + kk] + smem[(1 * 64 + l) * 65 + kk] +
                    smem[(2 * 64 + l) * 65 + kk] + smem[(3 * 64 + l) * 65 + kk];
        float as = asum[n * 64 + kk];               // uniform -> scalar
        float vv = vocabs[kk * 512 + c];            // coalesced
        float cor = fmaf(-as, vv, val);
        out[(size_t)n * 32768 + (size_t)kk * 512 + c] = cor;
        float t2 = cor * cor;
#pragma unroll
        for (int off = 32; off > 0; off >>= 1) t2 += __shfl_xor(t2, off, 64);
        if (l == 0) atomicAdd(&knorm[n * 64 + kk], t2);
    }
}

// ---------------- scale: intra-norm (per k) * global norm (per n), in place -
__global__ __launch_bounds__(256) void scale_kernel(float* __restrict__ out,
                                                    const float* __restrict__ knorm) {
    int n = blockIdx.y;
    int s = blockIdx.x;  // 0..7 slice of 4096
    int tid = threadIdx.x;
    __shared__ float sc[64];
    __shared__ float tots;
    if (tid < 64) {
        float kn = knorm[n * 64 + tid];
        float nk = sqrtf(kn);
        float inv = 1.0f / fmaxf(nk, EPSN);
        sc[tid] = inv;
        float t = nk * inv;
        float t2 = t * t;
#pragma unroll
        for (int off = 32; off > 0; off >>= 1) t2 += __shfl_xor(t2, off, 64);
        if (tid == 0) tots = t2;
    }
    __syncthreads();
    float invt = 1.0f / fmaxf(sqrtf(tots), EPSN);
    float* base = out + (size_t)n * 32768 + s * 4096;
#pragma unroll
    for (int i = 0; i < 16; ++i) {
        int idx = tid + 256 * i;
        int k = (s * 4096 + idx) >> 9;
        base[idx] *= sc[k] * invt;
    }
}

extern "C" void kernel_launch(void* const* d_in, const int* in_sizes, int n_in,
                              void* d_out, int out_size, void* d_ws, size_t ws_size,
                              hipStream_t stream) {
    const float* x = (const float*)d_in[0];       // [32,512,32,32]
    const float* vocabs = (const float*)d_in[1];  // [64,512]
    float* out = (float*)d_out;                   // [32, 32768]
    char* ws = (char*)d_ws;
    float* vt    = (float*)(ws);             // 131072 B : vocab^T [c][k]
    float* bias  = (float*)(ws + 131072);    //    256 B
    float* asum  = (float*)(ws + 131328);    //   8192 B (memset 0)
    float* knorm = (float*)(ws + 139520);    //   8192 B (memset 0)
    float* sinv  = (float*)(ws + 147712);    // 131072 B
    float* aT    = (float*)(ws + 278784);    //   8 MB : a^T [n][k][p]

    hipMemsetAsync(asum, 0, 16384, stream);  // asum + knorm contiguous
    prep_kernel<<<64, 64, 0, stream>>>(vocabs, vt, bias);
    assign_kernel<<<512, 512, 0, stream>>>(x, vt, bias, aT, asum, sinv);
    vlad_kernel<<<dim3(8, 32), 512, 0, stream>>>(x, aT, sinv, asum, vocabs, out,
                                                 knorm);
    scale_kernel<<<dim3(8, 32), 256, 0, stream>>>(out, knorm);
}

// Round 3
// 143.492 us; speedup vs baseline: 1.7826x; 1.7826x over previous
//
#include <hip/hip_runtime.h>
#include <math.h>
#include <stdint.h>

// NetVLAD: N=32, C=512, P=1024, K=64, ALPHA=100. Split-bf16 MFMA version.
#define ALPHA 100.0f
#define EPSN 1e-12f

typedef __attribute__((ext_vector_type(8))) short bf16x8;    // 8 bf16 = 4 VGPR
typedef __attribute__((ext_vector_type(16))) float f32x16;   // 32x32 acc
typedef __attribute__((ext_vector_type(4))) unsigned int u32x4;

static __device__ __forceinline__ unsigned int f2bf(float f) {
    unsigned int u = __builtin_bit_cast(unsigned int, f);
    return (u + 0x7FFFu + ((u >> 16) & 1u)) >> 16;  // RNE
}
static __device__ __forceinline__ float bf2f(unsigned int b) {
    return __builtin_bit_cast(float, b << 16);
}

// ---------------- prep: v -> (vh, vl) bf16 split [k][c]; bias[k] ------------
__global__ __launch_bounds__(64) void prep_kernel(const float* __restrict__ v,
                                                  unsigned short* __restrict__ vh,
                                                  unsigned short* __restrict__ vl,
                                                  float* __restrict__ bias) {
    int k = blockIdx.x, lane = threadIdx.x;
    const float* row = v + k * 512;
    float ssq = 0.f;
#pragma unroll
    for (int i = 0; i < 8; ++i) {
        int c = lane + 64 * i;
        float f = row[c];
        ssq = fmaf(f, f, ssq);
        unsigned int hi = f2bf(f);
        unsigned int lo = f2bf(f - bf2f(hi));
        vh[k * 512 + c] = (unsigned short)hi;
        vl[k * 512 + c] = (unsigned short)lo;
    }
#pragma unroll
    for (int off = 32; off > 0; off >>= 1) ssq += __shfl_xor(ssq, off, 64);
    if (lane == 0) bias[k] = -ALPHA * sqrtf(ssq);
}

// ---------------- P1: D[k][p] = sum_c v[k][c]*x[c][p] (3-pass split bf16) ---
// grid 256 = (n, p-block of 128). block 256 thr = 4 waves, wave = 64k x 32p.
__global__ __launch_bounds__(256) void assign_kernel(
    const float* __restrict__ x, const unsigned short* __restrict__ vh,
    const unsigned short* __restrict__ vl, const float* __restrict__ bias,
    unsigned short* __restrict__ aT, float* __restrict__ asum,
    float* __restrict__ sinv_g) {
    __shared__ __align__(16) uint32_t xt[32 * 130];   // packed(hi,lo) x [c][p]
    __shared__ __align__(16) uint32_t vt_h[64 * 20];  // vh tile [k][c-chunk]
    __shared__ __align__(16) uint32_t vt_l[64 * 20];
    __shared__ float ssq_lds[256];
    __shared__ float bias_l[64];

    int tid = threadIdx.x, bx = blockIdx.x;
    int n = bx >> 3;
    int pblk = (bx & 7) << 7;
    int lane = tid & 63, w = tid >> 6, h = lane >> 5, cl = lane & 31;

    if (tid < 64) bias_l[tid] = bias[tid];

    const float* xg = x + (size_t)n * 524288 + pblk;
    int ps = tid & 127;   // staging p (fixed per thread)
    int chalf = tid >> 7; // c parity
    int ks = tid >> 2, js = tid & 3;

    f32x16 acc0, acc1;
#pragma unroll
    for (int r = 0; r < 16; ++r) { acc0[r] = 0.f; acc1[r] = 0.f; }
    float ssq = 0.f;

    float px[16];
    u32x4 pvh, pvl;
#pragma unroll
    for (int i = 0; i < 16; ++i)
        px[i] = xg[(size_t)(chalf + 2 * i) * 1024 + ps];
    pvh = *(const u32x4*)(vh + ks * 512 + js * 8);
    pvl = *(const u32x4*)(vl + ks * 512 + js * 8);

    for (int ch = 0; ch < 16; ++ch) {
        __syncthreads();
#pragma unroll
        for (int i = 0; i < 16; ++i) {
            float f = px[i];
            ssq = fmaf(f, f, ssq);
            unsigned int hi = f2bf(f);
            unsigned int lo = f2bf(f - bf2f(hi));
            xt[(chalf + 2 * i) * 130 + ps] = (hi << 16) | lo;
        }
        *(u32x4*)&vt_h[ks * 20 + js * 4] = pvh;
        *(u32x4*)&vt_l[ks * 20 + js * 4] = pvl;
        __syncthreads();
        if (ch < 15) {
            int c0 = (ch + 1) * 32;
#pragma unroll
            for (int i = 0; i < 16; ++i)
                px[i] = xg[(size_t)(c0 + chalf + 2 * i) * 1024 + ps];
            pvh = *(const u32x4*)(vh + ks * 512 + c0 + js * 8);
            pvl = *(const u32x4*)(vl + ks * 512 + c0 + js * 8);
        }
#pragma unroll
        for (int s = 0; s < 2; ++s) {
            bf16x8 ah0 = *(const bf16x8*)&vt_h[cl * 20 + 8 * s + 4 * h];
            bf16x8 ah1 = *(const bf16x8*)&vt_h[(cl + 32) * 20 + 8 * s + 4 * h];
            bf16x8 al0 = *(const bf16x8*)&vt_l[cl * 20 + 8 * s + 4 * h];
            bf16x8 al1 = *(const bf16x8*)&vt_l[(cl + 32) * 20 + 8 * s + 4 * h];
            uint32_t wv[8];
#pragma unroll
            for (int j = 0; j < 8; ++j)
                wv[j] = xt[(16 * s + 8 * h + j) * 130 + w * 32 + cl];
            u32x4 bhp, blp;
#pragma unroll
            for (int i = 0; i < 4; ++i) {
                bhp[i] = (wv[2 * i] >> 16) | (wv[2 * i + 1] & 0xFFFF0000u);
                blp[i] = (wv[2 * i] & 0xFFFFu) | (wv[2 * i + 1] << 16);
            }
            bf16x8 bh = __builtin_bit_cast(bf16x8, bhp);
            bf16x8 bl = __builtin_bit_cast(bf16x8, blp);
            acc0 = __builtin_amdgcn_mfma_f32_32x32x16_bf16(ah0, bh, acc0, 0, 0, 0);
            acc1 = __builtin_amdgcn_mfma_f32_32x32x16_bf16(ah1, bh, acc1, 0, 0, 0);
            acc0 = __builtin_amdgcn_mfma_f32_32x32x16_bf16(ah0, bl, acc0, 0, 0, 0);
            acc1 = __builtin_amdgcn_mfma_f32_32x32x16_bf16(ah1, bl, acc1, 0, 0, 0);
            acc0 = __builtin_amdgcn_mfma_f32_32x32x16_bf16(al0, bh, acc0, 0, 0, 0);
            acc1 = __builtin_amdgcn_mfma_f32_32x32x16_bf16(al1, bh, acc1, 0, 0, 0);
        }
    }
    ssq_lds[tid] = ssq;
    __syncthreads();

    // epilogue: logits -> softmax over 64 k (32 in-lane + shfl_xor 32)
    int p_l = w * 32 + cl;
    float ssqv = ssq_lds[p_l] + ssq_lds[p_l + 128];
    float sv = 1.0f / fmaxf(sqrtf(ssqv), EPSN);
    if (h == 0) sinv_g[n * 1024 + pblk + p_l] = sv;
    float twoAs = 2.0f * ALPHA * sv;
    float e[2][16];
    float m = -INFINITY;
#pragma unroll
    for (int t = 0; t < 2; ++t)
#pragma unroll
        for (int r = 0; r < 16; ++r) {
            int k = (r & 3) + 8 * (r >> 2) + 4 * h + 32 * t;
            float lv = fmaf(twoAs, (t ? acc1[r] : acc0[r]), bias_l[k]);
            e[t][r] = lv;
            m = fmaxf(m, lv);
        }
    m = fmaxf(m, __shfl_xor(m, 32, 64));
    float s = 0.f;
#pragma unroll
    for (int t = 0; t < 2; ++t)
#pragma unroll
        for (int r = 0; r < 16; ++r) {
            e[t][r] = expf(e[t][r] - m);
            s += e[t][r];
        }
    s += __shfl_xor(s, 32, 64);
    float rs = 1.0f / s;
    unsigned short* aTn = aT + (size_t)n * 65536 + pblk + p_l;
#pragma unroll
    for (int t = 0; t < 2; ++t)
#pragma unroll
        for (int r = 0; r < 16; ++r) {
            int k = (r & 3) + 8 * (r >> 2) + 4 * h + 32 * t;
            float a = e[t][r] * rs;
            aTn[(size_t)k * 1024] = (unsigned short)f2bf(a);
            float red = a;
#pragma unroll
            for (int off = 1; off <= 16; off <<= 1) red += __shfl_xor(red, off, 64);
            if (cl == 0) atomicAdd(&asum[n * 64 + k], red);
        }
}

// ---------------- P2: D[k][c] = sum_p aT[k][p]*xhat[c][p]; -asum*v fused ----
// grid 256 = (n, c-oct of 64). block 256 thr = 4 waves, wave = 32k x 32c.
__global__ __launch_bounds__(256) void vlad_kernel(
    const float* __restrict__ x, const unsigned short* __restrict__ aT,
    const float* __restrict__ sinv_g, const float* __restrict__ asum,
    const float* __restrict__ vocabs, float* __restrict__ out,
    float* __restrict__ knorm) {
    __shared__ __align__(16) uint32_t xt[64 * 36];  // xhat bf16 [c][p-pair]
    __shared__ __align__(16) uint32_t at[64 * 36];  // a bf16 [k][p-pair]
    __shared__ float sinv_l[1024];
    __shared__ float asum_l[64];

    int tid = threadIdx.x, bx = blockIdx.x;
    int n = bx >> 3;
    int cblk = (bx & 7) << 6;
    int lane = tid & 63, w = tid >> 6, h = lane >> 5, cl = lane & 31;
    int wk = w & 1, wc = w >> 1;

    ((float4*)sinv_l)[tid] = ((const float4*)(sinv_g + n * 1024))[tid];
    if (tid < 64) asum_l[tid] = asum[n * 64 + tid];

    int ph = tid & 31;  // p-pair index
    int cs = tid >> 5;  // c-row slot
    int ks = tid >> 2, js = tid & 3;

    const float* xg = x + (size_t)n * 524288 + (size_t)cblk * 1024;
    const unsigned short* ag = aT + (size_t)n * 65536;

    f32x16 acc;
#pragma unroll
    for (int r = 0; r < 16; ++r) acc[r] = 0.f;

    float2 qx[8];
    u32x4 qa0, qa1;
#pragma unroll
    for (int i = 0; i < 8; ++i)
        qx[i] = *(const float2*)(xg + (size_t)(cs + 8 * i) * 1024 + 2 * ph);
    qa0 = *(const u32x4*)(ag + ks * 1024 + js * 16);
    qa1 = *(const u32x4*)(ag + ks * 1024 + js * 16 + 8);
    __syncthreads();  // sinv_l ready

    for (int chp = 0; chp < 16; ++chp) {
        int p0 = chp * 64;
        float s0 = sinv_l[p0 + 2 * ph];
        float s1 = sinv_l[p0 + 2 * ph + 1];
#pragma unroll
        for (int i = 0; i < 8; ++i) {
            unsigned int b0 = f2bf(qx[i].x * s0);
            unsigned int b1 = f2bf(qx[i].y * s1);
            xt[(cs + 8 * i) * 36 + ph] = b0 | (b1 << 16);
        }
        *(u32x4*)&at[ks * 36 + js * 8] = qa0;
        *(u32x4*)&at[ks * 36 + js * 8 + 4] = qa1;
        __syncthreads();
        if (chp < 15) {
            int p1 = p0 + 64;
#pragma unroll
            for (int i = 0; i < 8; ++i)
                qx[i] = *(const float2*)(xg + (size_t)(cs + 8 * i) * 1024 + p1 + 2 * ph);
            qa0 = *(const u32x4*)(ag + ks * 1024 + p1 + js * 16);
            qa1 = *(const u32x4*)(ag + ks * 1024 + p1 + js * 16 + 8);
        }
#pragma unroll
        for (int s = 0; s < 4; ++s) {
            bf16x8 af = *(const bf16x8*)&at[(32 * wk + cl) * 36 + 8 * s + 4 * h];
            bf16x8 bf = *(const bf16x8*)&xt[(32 * wc + cl) * 36 + 8 * s + 4 * h];
            acc = __builtin_amdgcn_mfma_f32_32x32x16_bf16(af, bf, acc, 0, 0, 0);
        }
        __syncthreads();  // protect tiles before next commit
    }
    // epilogue: -asum*v, store raw, knorm atomics
#pragma unroll
    for (int r = 0; r < 16; ++r) {
        int k = (r & 3) + 8 * (r >> 2) + 4 * h + 32 * wk;
        int c = cblk + 32 * wc + cl;
        float val = fmaf(-asum_l[k], vocabs[k * 512 + c], acc[r]);
        out[(size_t)n * 32768 + (size_t)k * 512 + c] = val;
        float t2 = val * val;
#pragma unroll
        for (int off = 1; off <= 16; off <<= 1) t2 += __shfl_xor(t2, off, 64);
        if (cl == 0) atomicAdd(&knorm[n * 64 + k], t2);
    }
}

// ---------------- scale: intra-norm (per k) * global norm (per n), in place -
__global__ __launch_bounds__(256) void scale_kernel(float* __restrict__ out,
                                                    const float* __restrict__ knorm) {
    int n = blockIdx.y;
    int sb = blockIdx.x;
    int tid = threadIdx.x;
    __shared__ float sc[64];
    __shared__ float tots;
    if (tid < 64) {
        float kn = knorm[n * 64 + tid];
        float nk = sqrtf(kn);
        float inv = 1.0f / fmaxf(nk, EPSN);
        sc[tid] = inv;
        float t = nk * inv;
        float t2 = t * t;
#pragma unroll
        for (int off = 32; off > 0; off >>= 1) t2 += __shfl_xor(t2, off, 64);
        if (tid == 0) tots = t2;
    }
    __syncthreads();
    float invt = 1.0f / fmaxf(sqrtf(tots), EPSN);
    float* base = out + (size_t)n * 32768 + sb * 4096;
#pragma unroll
    for (int i = 0; i < 16; ++i) {
        int idx = tid + 256 * i;
        int k = (sb * 4096 + idx) >> 9;
        base[idx] *= sc[k] * invt;
    }
}

extern "C" void kernel_launch(void* const* d_in, const int* in_sizes, int n_in,
                              void* d_out, int out_size, void* d_ws, size_t ws_size,
                              hipStream_t stream) {
    const float* x = (const float*)d_in[0];       // [32,512,32,32]
    const float* vocabs = (const float*)d_in[1];  // [64,512]
    float* out = (float*)d_out;                   // [32, 32768]
    char* ws = (char*)d_ws;
    unsigned short* vh = (unsigned short*)(ws);            // 65536 B
    unsigned short* vl = (unsigned short*)(ws + 65536);    // 65536 B
    float* bias  = (float*)(ws + 131072);                  //   256 B
    float* asum  = (float*)(ws + 131328);                  //  8192 B (memset)
    float* knorm = (float*)(ws + 139520);                  //  8192 B (memset)
    float* sinv  = (float*)(ws + 147712);                  // 131072 B
    unsigned short* aT = (unsigned short*)(ws + 278784);   // 4 MB [n][k][p]

    hipMemsetAsync(asum, 0, 16384, stream);  // asum + knorm contiguous
    prep_kernel<<<64, 64, 0, stream>>>(vocabs, vh, vl, bias);
    assign_kernel<<<256, 256, 0, stream>>>(x, vh, vl, bias, aT, asum, sinv);
    vlad_kernel<<<256, 256, 0, stream>>>(x, aT, sinv, asum, vocabs, out, knorm);
    scale_kernel<<<dim3(8, 32), 256, 0, stream>>>(out, knorm);
}